// Round 1
// baseline (577.662 us; speedup 1.0000x reference)
//
#include <hip/hip_runtime.h>
#include <hip/hip_bf16.h>
#include <stdint.h>
#include <stddef.h>

#define B_ 8
#define S_ 2048
#define E_ 1024
#define H_ 128

typedef __attribute__((ext_vector_type(8))) short short8;   // 8 x bf16 (4 VGPRs)
typedef __attribute__((ext_vector_type(4))) float f32x4;

__device__ __forceinline__ short f2bf(float f){
  uint32_t u = __builtin_bit_cast(uint32_t, f);
  u = (u + 0x7FFFu + ((u >> 16) & 1u)) >> 16;   // RNE
  return (short)(uint16_t)u;
}

// ---------------------------------------------------------------------------
// wq/wk/wv [E][H] f32  ->  wt [3*H][E] bf16 (transposed so B-frags are
// contiguous along K for mfma_f32_16x16x32_bf16)
// ---------------------------------------------------------------------------
__global__ void pack_w(const float* __restrict__ wq, const float* __restrict__ wk,
                       const float* __restrict__ wv, short* __restrict__ wt){
  int idx = blockIdx.x * 256 + threadIdx.x;       // 3*H*E = 393216
  int e   = idx & (E_ - 1);
  int he  = idx >> 10;
  int h   = he & (H_ - 1);
  int w   = he >> 7;
  const float* src = (w == 0) ? wq : (w == 1) ? wk : wv;
  wt[idx] = f2bf(src[e * H_ + h]);
}

// ---------------------------------------------------------------------------
// QKV GEMM: [16384 x 1024] x [1024 x 384] -> q,k bf16 [B*S][H], v -> vtmp
// One block = 4 waves; each wave does a 16(M) x 384(N) slab, K-loop step 32.
// A-frag: A[m=lane%16][k=quad*8+j]  (x rows, cast f32->bf16 in flight)
// B-frag: B[k][n=lane%16] = wt[n][k] (16B contiguous loads)
// C/D:    D[row=quad*4+r][col=lane%16]
// ---------------------------------------------------------------------------
__launch_bounds__(256)
__global__ void qkv_gemm(const float* __restrict__ x, const short* __restrict__ wt,
                         short* __restrict__ qm, short* __restrict__ km,
                         short* __restrict__ vtmp){
  const int wave = threadIdx.x >> 6;
  const int lane = threadIdx.x & 63;
  const int l16  = lane & 15;
  const int quad = lane >> 4;
  const int m0   = blockIdx.x * 64 + wave * 16;

  const float* xrow = x  + (size_t)(m0 + l16) * E_ + quad * 8;
  const short* wb   = wt + (size_t)l16 * E_ + quad * 8;

  f32x4 acc[24];
#pragma unroll
  for (int i = 0; i < 24; i++) acc[i] = (f32x4)(0.0f);

  for (int k0 = 0; k0 < E_; k0 += 32){
    f32x4 a0 = *(const f32x4*)(xrow + k0);
    f32x4 a1 = *(const f32x4*)(xrow + k0 + 4);
    short8 af;
    af[0]=f2bf(a0[0]); af[1]=f2bf(a0[1]); af[2]=f2bf(a0[2]); af[3]=f2bf(a0[3]);
    af[4]=f2bf(a1[0]); af[5]=f2bf(a1[1]); af[6]=f2bf(a1[2]); af[7]=f2bf(a1[3]);
#pragma unroll
    for (int nt = 0; nt < 24; nt++){
      short8 bf = *(const short8*)(wb + (size_t)nt * 16 * E_ + k0);
      acc[nt] = __builtin_amdgcn_mfma_f32_16x16x32_bf16(af, bf, acc[nt], 0, 0, 0);
    }
  }

#pragma unroll
  for (int nt = 0; nt < 24; nt++){
    int ncol = (nt & 7) * 16 + l16;               // n mod 128
    short* dst = (nt < 8) ? qm : (nt < 16) ? km : vtmp;
#pragma unroll
    for (int r = 0; r < 4; r++){
      int mrow = m0 + quad * 4 + r;
      dst[(size_t)mrow * H_ + ncol] = f2bf(acc[nt][r]);
    }
  }
}

// ---------------------------------------------------------------------------
// vtmp [B][S][H] -> vt [B][H][S]  (so PV B-frags are contiguous along t)
// ---------------------------------------------------------------------------
__global__ void transpose_v(const short* __restrict__ v, short* __restrict__ vt){
  __shared__ short t[32][33];
  int idx = blockIdx.x;             // 8 * 64 * 4 = 2048 blocks
  int hb = idx & 3;
  int sb = (idx >> 2) & 63;
  int b  = idx >> 8;
  int s0 = sb * 32, h0 = hb * 32;
  int c  = threadIdx.x & 31;
  int r0 = threadIdx.x >> 5;        // 0..7
#pragma unroll
  for (int i = 0; i < 4; i++){
    int r = r0 * 4 + i;
    t[r][c] = v[((size_t)b * S_ + s0 + r) * H_ + h0 + c];
  }
  __syncthreads();
#pragma unroll
  for (int i = 0; i < 4; i++){
    int r = r0 * 4 + i;
    vt[((size_t)b * H_ + h0 + r) * S_ + s0 + c] = t[c][r];
  }
}

// ---------------------------------------------------------------------------
// Flash-style attention. Block = 4 waves; wave owns 16 q-rows, iterates key
// tiles of 64. Softmax in exp2 domain (scores pre-scaled by E^-0.5 * log2 e).
// Dropout applied AFTER the l-sum (reference normalizes before dropout).
// P: C-layout -> LDS -> A-layout (verified m120 pattern), then PV MFMA.
// ---------------------------------------------------------------------------
__launch_bounds__(256)
__global__ void attn(const short* __restrict__ qm, const short* __restrict__ km,
                     const short* __restrict__ vtm, const float* __restrict__ du,
                     float* __restrict__ out){
  const int wave = threadIdx.x >> 6;
  const int lane = threadIdx.x & 63;
  const int l16  = lane & 15;
  const int quad = lane >> 4;
  const int b    = blockIdx.x >> 5;             // 32 row-blocks per batch
  const int m0   = (blockIdx.x & 31) * 64 + wave * 16;

  const short* qb  = qm  + ((size_t)b * S_ + m0) * H_;
  const short* kb  = km  + (size_t)b * S_ * H_;
  const short* vb  = vtm + (size_t)b * H_ * S_;
  const float* dub = du  + ((size_t)b * S_ + m0) * S_;

  short8 qf[4];
#pragma unroll
  for (int kc = 0; kc < 4; kc++)
    qf[kc] = *(const short8*)(qb + (size_t)l16 * H_ + kc * 32 + quad * 8);

  f32x4 o[8];
#pragma unroll
  for (int ht = 0; ht < 8; ht++) o[ht] = (f32x4)(0.0f);
  float mrow[4] = {-INFINITY, -INFINITY, -INFINITY, -INFINITY};
  float lrow[4] = {0.f, 0.f, 0.f, 0.f};

  // 16 rows x 64 cols bf16 per wave; row stride 72*2=144 B (16B-aligned, pads banks)
  __shared__ __align__(16) short pbuf[4][16][72];
  const float SC2 = 0.045084220f;               // (1/32) * log2(e)

  for (int t0 = 0; t0 < S_; t0 += 64){
    f32x4 s[4];
#pragma unroll
    for (int nt = 0; nt < 4; nt++) s[nt] = (f32x4)(0.0f);
#pragma unroll
    for (int nt = 0; nt < 4; nt++){
      const short* kt = kb + (size_t)(t0 + nt * 16 + l16) * H_ + quad * 8;
#pragma unroll
      for (int kc = 0; kc < 4; kc++){
        short8 bf = *(const short8*)(kt + kc * 32);
        s[nt] = __builtin_amdgcn_mfma_f32_16x16x32_bf16(qf[kc], bf, s[nt], 0, 0, 0);
      }
    }
#pragma unroll
    for (int nt = 0; nt < 4; nt++)
#pragma unroll
      for (int r = 0; r < 4; r++) s[nt][r] *= SC2;

    float alpha[4];
#pragma unroll
    for (int r = 0; r < 4; r++){
      float v = fmaxf(fmaxf(s[0][r], s[1][r]), fmaxf(s[2][r], s[3][r]));
      v = fmaxf(v, __shfl_xor(v, 1));
      v = fmaxf(v, __shfl_xor(v, 2));
      v = fmaxf(v, __shfl_xor(v, 4));
      v = fmaxf(v, __shfl_xor(v, 8));
      float mnew = fmaxf(mrow[r], v);
      alpha[r] = exp2f(mrow[r] - mnew);
      float sum = 0.f;
#pragma unroll
      for (int nt = 0; nt < 4; nt++){
        float p = exp2f(s[nt][r] - mnew);
        s[nt][r] = p;
        sum += p;
      }
      sum += __shfl_xor(sum, 1);
      sum += __shfl_xor(sum, 2);
      sum += __shfl_xor(sum, 4);
      sum += __shfl_xor(sum, 8);
      lrow[r] = lrow[r] * alpha[r] + sum;
      mrow[r] = mnew;
    }
#pragma unroll
    for (int ht = 0; ht < 8; ht++)
#pragma unroll
      for (int r = 0; r < 4; r++) o[ht][r] *= alpha[r];

    // dropout (post-normalization) + stage P into LDS in C-layout positions
#pragma unroll
    for (int nt = 0; nt < 4; nt++)
#pragma unroll
      for (int r = 0; r < 4; r++){
        float u  = dub[(size_t)(quad * 4 + r) * S_ + (t0 + nt * 16 + l16)];
        float pv = (u >= 0.1f) ? s[nt][r] * (1.0f / 0.9f) : 0.0f;
        pbuf[wave][quad * 4 + r][nt * 16 + l16] = f2bf(pv);
      }
    __syncthreads();
    short8 pf0 = *(const short8*)&pbuf[wave][l16][quad * 8];
    short8 pf1 = *(const short8*)&pbuf[wave][l16][32 + quad * 8];
#pragma unroll
    for (int ht = 0; ht < 8; ht++){
      const short* vp = vb + (size_t)(ht * 16 + l16) * S_ + t0 + quad * 8;
      o[ht] = __builtin_amdgcn_mfma_f32_16x16x32_bf16(pf0, *(const short8*)vp, o[ht], 0, 0, 0);
      o[ht] = __builtin_amdgcn_mfma_f32_16x16x32_bf16(pf1, *(const short8*)(vp + 32), o[ht], 0, 0, 0);
    }
    __syncthreads();
  }

  float* op = out + ((size_t)b * S_ + m0) * H_;
#pragma unroll
  for (int ht = 0; ht < 8; ht++)
#pragma unroll
    for (int r = 0; r < 4; r++)
      op[(size_t)(quad * 4 + r) * H_ + ht * 16 + l16] = o[ht][r] / lrow[r];
}

// ---------------------------------------------------------------------------
extern "C" void kernel_launch(void* const* d_in, const int* in_sizes, int n_in,
                              void* d_out, int out_size, void* d_ws, size_t ws_size,
                              hipStream_t stream){
  const float* x  = (const float*)d_in[0];
  const float* wq = (const float*)d_in[1];
  const float* wk = (const float*)d_in[2];
  const float* wv = (const float*)d_in[3];
  const float* du = (const float*)d_in[4];
  float* out = (float*)d_out;

  char* ws = (char*)d_ws;
  short* wt   = (short*)(ws);                                 // 786432 B
  short* qm   = (short*)(ws + 786432);                        // 4 MiB
  short* km   = (short*)(ws + 786432 + 1 * 4194304);          // 4 MiB
  short* vtmp = (short*)(ws + 786432 + 2 * 4194304);          // 4 MiB
  short* vtm  = (short*)(ws + 786432 + 3 * 4194304);          // 4 MiB

  hipLaunchKernelGGL(pack_w,      dim3(1536), dim3(256), 0, stream, wq, wk, wv, wt);
  hipLaunchKernelGGL(qkv_gemm,    dim3(256),  dim3(256), 0, stream, x, wt, qm, km, vtmp);
  hipLaunchKernelGGL(transpose_v, dim3(2048), dim3(256), 0, stream, vtmp, vtm);
  hipLaunchKernelGGL(attn,        dim3(256),  dim3(256), 0, stream, qm, km, vtm, du, out);
}

// Round 2
// 442.215 us; speedup vs baseline: 1.3063x; 1.3063x over previous
//
#include <hip/hip_runtime.h>
#include <hip/hip_bf16.h>
#include <stdint.h>
#include <stddef.h>

#define B_ 8
#define S_ 2048
#define E_ 1024
#define H_ 128
#define NR_ (B_ * S_)   // 16384 total q-rows

typedef __attribute__((ext_vector_type(8))) short short8;   // 8 x bf16 (4 VGPRs)
typedef __attribute__((ext_vector_type(4))) float f32x4;

__device__ __forceinline__ short f2bf(float f){
  uint32_t u = __builtin_bit_cast(uint32_t, f);
  u = (u + 0x7FFFu + ((u >> 16) & 1u)) >> 16;   // RNE
  return (short)(uint16_t)u;
}

#define GLOBAL_AS __attribute__((address_space(1)))
#define LDS_AS    __attribute__((address_space(3)))
__device__ __forceinline__ void async16(const void* g, void* l){
  __builtin_amdgcn_global_load_lds((const GLOBAL_AS uint32_t*)g,
                                   (LDS_AS uint32_t*)l, 16, 0, 0);
}

// ---------------------------------------------------------------------------
// wq/wk/wv [E][H] f32 -> wt [3*H][E] bf16, coalesced both sides via LDS tile.
// grid = 3 * (E/32) * (H/32) = 384 blocks x 256 threads
// ---------------------------------------------------------------------------
__global__ void pack_w(const float* __restrict__ wq, const float* __restrict__ wk,
                       const float* __restrict__ wv, short* __restrict__ wt){
  __shared__ float t[32][33];
  int idx = blockIdx.x;
  int hb  = idx & 3;
  int eb  = (idx >> 2) & 31;
  int w   = idx >> 7;
  const float* src = (w == 0) ? wq : (w == 1) ? wk : wv;
  int c  = threadIdx.x & 31;
  int r0 = threadIdx.x >> 5;
#pragma unroll
  for (int i = 0; i < 4; i++){
    int r = r0 * 4 + i;
    t[r][c] = src[(size_t)(eb * 32 + r) * H_ + hb * 32 + c];   // coalesced along h
  }
  __syncthreads();
#pragma unroll
  for (int i = 0; i < 4; i++){
    int r = r0 * 4 + i;
    wt[(size_t)(w * 128 + hb * 32 + r) * E_ + eb * 32 + c] = f2bf(t[c][r]); // coalesced along e
  }
}

// ---------------------------------------------------------------------------
// QKV GEMM v2: LDS-staged. Block = 512 threads (8 waves), 64 rows x 384 cols.
// Wave (rg = wave>>2, g = wave&3) owns rows rg*32..+32, cols g*96..+96 (6 nt).
// wt k-slab (32 k x 384 n bf16 = 24.5 KB) staged per step via global_load_lds
// width 16 into slab[kchunk 4][n 384][8 k] (2-way LDS bank aliasing = free).
// A (x rows) loaded f32 from global, converted in-flight.
// ---------------------------------------------------------------------------
__launch_bounds__(512)
__global__ void qkv_gemm(const float* __restrict__ x, const short* __restrict__ wt,
                         short* __restrict__ qm, short* __restrict__ km,
                         short* __restrict__ vtmp){
  __shared__ __align__(16) short slab[12288];   // 24576 B
  const int tid  = threadIdx.x;
  const int wave = tid >> 6;
  const int lane = tid & 63;
  const int l16  = lane & 15;
  const int quad = lane >> 4;
  const int rg   = wave >> 2;        // 0..1
  const int g    = wave & 3;         // 0..3
  const int m0   = blockIdx.x * 64;

  f32x4 acc[2][6];
#pragma unroll
  for (int a = 0; a < 2; a++)
#pragma unroll
    for (int b = 0; b < 6; b++) acc[a][b] = (f32x4)(0.0f);

  const float* xr0 = x + (size_t)(m0 + rg * 32 + l16) * E_ + quad * 8;
  const float* xr1 = xr0 + (size_t)16 * E_;

  for (int k0 = 0; k0 < E_; k0 += 32){
    // ---- stage wt slab: 24 chunks of 1 KB, 3 per wave ----
#pragma unroll
    for (int i = 0; i < 3; i++){
      int c  = wave * 3 + i;          // 0..23
      int kc = c & 3;
      int nb = c >> 2;                // 0..5
      const short* gp = wt + (size_t)(nb * 64 + lane) * E_ + k0 + kc * 8;
      void* lp = (char*)slab + kc * 6144 + nb * 1024;
      async16(gp, lp);
    }
    __syncthreads();

    // ---- A fragments (2 m-tiles of 16 rows) ----
    f32x4 a00 = *(const f32x4*)(xr0 + k0);
    f32x4 a01 = *(const f32x4*)(xr0 + k0 + 4);
    f32x4 a10 = *(const f32x4*)(xr1 + k0);
    f32x4 a11 = *(const f32x4*)(xr1 + k0 + 4);
    short8 af0, af1;
#pragma unroll
    for (int j = 0; j < 4; j++){
      af0[j] = f2bf(a00[j]); af0[j + 4] = f2bf(a01[j]);
      af1[j] = f2bf(a10[j]); af1[j + 4] = f2bf(a11[j]);
    }

    // ---- 6 B-frags from LDS, 12 MFMA ----
#pragma unroll
    for (int j = 0; j < 6; j++){
      int nt = g * 6 + j;
      short8 bf = *(const short8*)((const char*)slab + quad * 6144 + (nt * 16 + l16) * 16);
      acc[0][j] = __builtin_amdgcn_mfma_f32_16x16x32_bf16(af0, bf, acc[0][j], 0, 0, 0);
      acc[1][j] = __builtin_amdgcn_mfma_f32_16x16x32_bf16(af1, bf, acc[1][j], 0, 0, 0);
    }
    __syncthreads();
  }

#pragma unroll
  for (int mt = 0; mt < 2; mt++)
#pragma unroll
    for (int j = 0; j < 6; j++){
      int c0  = g * 96 + j * 16;
      short* dst = (c0 < 128) ? qm : (c0 < 256) ? km : vtmp;
      int cin = c0 & 127;
      int row = m0 + rg * 32 + mt * 16 + quad * 4;
#pragma unroll
      for (int r = 0; r < 4; r++)
        dst[(size_t)(row + r) * H_ + cin + l16] = f2bf(acc[mt][j][r]);
    }
}

// ---------------------------------------------------------------------------
// vtmp [B][S][H] -> vt [B][H][S]
// ---------------------------------------------------------------------------
__global__ void transpose_v(const short* __restrict__ v, short* __restrict__ vt){
  __shared__ short t[32][33];
  int idx = blockIdx.x;             // 2048 blocks
  int hb = idx & 3;
  int sb = (idx >> 2) & 63;
  int b  = idx >> 8;
  int s0 = sb * 32, h0 = hb * 32;
  int c  = threadIdx.x & 31;
  int r0 = threadIdx.x >> 5;
#pragma unroll
  for (int i = 0; i < 4; i++){
    int r = r0 * 4 + i;
    t[r][c] = v[((size_t)b * S_ + s0 + r) * H_ + h0 + c];
  }
  __syncthreads();
#pragma unroll
  for (int i = 0; i < 4; i++){
    int r = r0 * 4 + i;
    vt[((size_t)b * H_ + h0 + r) * S_ + s0 + c] = t[c][r];
  }
}

// ---------------------------------------------------------------------------
// Flash attention with key-split. Block = 4 waves x 16 q-rows; handles keys
// [sp*seg, (sp+1)*seg). split>1: writes unnormalized partials (po, pm, pl).
// split==1: writes out directly. Dropout post-l-sum (matches reference).
// ---------------------------------------------------------------------------
__launch_bounds__(256)
__global__ void attn(const short* __restrict__ qm, const short* __restrict__ km,
                     const short* __restrict__ vtm, const float* __restrict__ du,
                     float* __restrict__ po, float* __restrict__ pm,
                     float* __restrict__ pl, float* __restrict__ out, int split){
  const int wave = threadIdx.x >> 6;
  const int lane = threadIdx.x & 63;
  const int l16  = lane & 15;
  const int quad = lane >> 4;
  const int sp   = blockIdx.x & (split - 1);    // split is 1/2/4
  const int rbk  = blockIdx.x / split;
  const int b    = rbk >> 5;
  const int m0   = (rbk & 31) * 64 + wave * 16;
  const int seg  = S_ / split;

  const short* qb  = qm  + ((size_t)b * S_ + m0) * H_;
  const short* kb  = km  + (size_t)b * S_ * H_;
  const short* vb  = vtm + (size_t)b * H_ * S_;
  const float* dub = du  + ((size_t)b * S_ + m0) * S_;

  short8 qf[4];
#pragma unroll
  for (int kc = 0; kc < 4; kc++)
    qf[kc] = *(const short8*)(qb + (size_t)l16 * H_ + kc * 32 + quad * 8);

  f32x4 o[8];
#pragma unroll
  for (int ht = 0; ht < 8; ht++) o[ht] = (f32x4)(0.0f);
  float mrow[4] = {-INFINITY, -INFINITY, -INFINITY, -INFINITY};
  float lrow[4] = {0.f, 0.f, 0.f, 0.f};

  __shared__ __align__(16) short pbuf[4][16][72];
  const float SC2 = 0.045084220f;               // (1/32) * log2(e)

  const int tbeg = sp * seg;
  for (int t0 = tbeg; t0 < tbeg + seg; t0 += 64){
    f32x4 s[4];
#pragma unroll
    for (int nt = 0; nt < 4; nt++) s[nt] = (f32x4)(0.0f);
#pragma unroll
    for (int nt = 0; nt < 4; nt++){
      const short* kt = kb + (size_t)(t0 + nt * 16 + l16) * H_ + quad * 8;
#pragma unroll
      for (int kc = 0; kc < 4; kc++){
        short8 bf = *(const short8*)(kt + kc * 32);
        s[nt] = __builtin_amdgcn_mfma_f32_16x16x32_bf16(qf[kc], bf, s[nt], 0, 0, 0);
      }
    }
#pragma unroll
    for (int nt = 0; nt < 4; nt++)
#pragma unroll
      for (int r = 0; r < 4; r++) s[nt][r] *= SC2;

    float alpha[4];
#pragma unroll
    for (int r = 0; r < 4; r++){
      float v = fmaxf(fmaxf(s[0][r], s[1][r]), fmaxf(s[2][r], s[3][r]));
      v = fmaxf(v, __shfl_xor(v, 1));
      v = fmaxf(v, __shfl_xor(v, 2));
      v = fmaxf(v, __shfl_xor(v, 4));
      v = fmaxf(v, __shfl_xor(v, 8));
      float mnew = fmaxf(mrow[r], v);
      alpha[r] = exp2f(mrow[r] - mnew);
      float sum = 0.f;
#pragma unroll
      for (int nt = 0; nt < 4; nt++){
        float p = exp2f(s[nt][r] - mnew);
        s[nt][r] = p;
        sum += p;
      }
      sum += __shfl_xor(sum, 1);
      sum += __shfl_xor(sum, 2);
      sum += __shfl_xor(sum, 4);
      sum += __shfl_xor(sum, 8);
      lrow[r] = lrow[r] * alpha[r] + sum;
      mrow[r] = mnew;
    }
#pragma unroll
    for (int ht = 0; ht < 8; ht++)
#pragma unroll
      for (int r = 0; r < 4; r++) o[ht][r] *= alpha[r];

#pragma unroll
    for (int nt = 0; nt < 4; nt++)
#pragma unroll
      for (int r = 0; r < 4; r++){
        float u  = dub[(size_t)(quad * 4 + r) * S_ + (t0 + nt * 16 + l16)];
        float pv = (u >= 0.1f) ? s[nt][r] * (1.0f / 0.9f) : 0.0f;
        pbuf[wave][quad * 4 + r][nt * 16 + l16] = f2bf(pv);
      }
    __syncthreads();
    short8 pf0 = *(const short8*)&pbuf[wave][l16][quad * 8];
    short8 pf1 = *(const short8*)&pbuf[wave][l16][32 + quad * 8];
#pragma unroll
    for (int ht = 0; ht < 8; ht++){
      const short* vp = vb + (size_t)(ht * 16 + l16) * S_ + t0 + quad * 8;
      o[ht] = __builtin_amdgcn_mfma_f32_16x16x32_bf16(pf0, *(const short8*)vp, o[ht], 0, 0, 0);
      o[ht] = __builtin_amdgcn_mfma_f32_16x16x32_bf16(pf1, *(const short8*)(vp + 32), o[ht], 0, 0, 0);
    }
    __syncthreads();
  }

  if (split == 1){
    float* op = out + ((size_t)b * S_ + m0) * H_;
#pragma unroll
    for (int ht = 0; ht < 8; ht++)
#pragma unroll
      for (int r = 0; r < 4; r++)
        op[(size_t)(quad * 4 + r) * H_ + ht * 16 + l16] = o[ht][r] / lrow[r];
  } else {
#pragma unroll
    for (int r = 0; r < 4; r++){
      size_t R = (size_t)b * S_ + m0 + quad * 4 + r;
#pragma unroll
      for (int ht = 0; ht < 8; ht++)
        po[((size_t)sp * NR_ + R) * H_ + ht * 16 + l16] = o[ht][r];
      if (l16 == 0){
        pm[(size_t)sp * NR_ + R] = mrow[r];
        pl[(size_t)sp * NR_ + R] = lrow[r];
      }
    }
  }
}

// ---------------------------------------------------------------------------
// Merge split partials: out = sum_s(o_s * 2^(m_s-M)) / sum_s(l_s * 2^(m_s-M))
// grid = 16384 blocks x 128 threads
// ---------------------------------------------------------------------------
__global__ void combine(const float* __restrict__ po, const float* __restrict__ pm,
                        const float* __restrict__ pl, float* __restrict__ out,
                        int split){
  int row = blockIdx.x;
  int col = threadIdx.x;
  float M = -INFINITY;
  for (int s = 0; s < split; s++) M = fmaxf(M, pm[(size_t)s * NR_ + row]);
  float num = 0.f, den = 0.f;
  for (int s = 0; s < split; s++){
    float w = exp2f(pm[(size_t)s * NR_ + row] - M);
    num += po[((size_t)s * NR_ + row) * H_ + col] * w;
    den += pl[(size_t)s * NR_ + row] * w;
  }
  out[(size_t)row * H_ + col] = num / den;
}

// ---------------------------------------------------------------------------
extern "C" void kernel_launch(void* const* d_in, const int* in_sizes, int n_in,
                              void* d_out, int out_size, void* d_ws, size_t ws_size,
                              hipStream_t stream){
  const float* x  = (const float*)d_in[0];
  const float* wq = (const float*)d_in[1];
  const float* wk = (const float*)d_in[2];
  const float* wv = (const float*)d_in[3];
  const float* du = (const float*)d_in[4];
  float* out = (float*)d_out;

  const size_t MiB = 1048576;
  char* ws = (char*)d_ws;
  short* qm  = (short*)(ws);                       // 4 MiB
  short* km  = (short*)(ws + 4 * MiB);             // 4 MiB
  short* vt  = (short*)(ws + 8 * MiB);             // 4 MiB
  float* pm  = (float*)(ws + 12 * MiB);            // <=256 KiB
  float* pl  = (float*)(ws + 12 * MiB + 262144);   // <=256 KiB
  float* po  = (float*)(ws + 12 * MiB + 524288);   // split*8 MiB
  // wt/vtmp alias the po region (dead before attn writes po)
  short* wt   = (short*)(ws + 12 * MiB + 524288);            // 768 KiB
  short* vtmp = (short*)(ws + 12 * MiB + 524288 + 1 * MiB);  // 4 MiB

  size_t base  = 12 * MiB + 524288;
  size_t need4 = base + 4 * 8 * MiB;
  size_t need2 = base + 2 * 8 * MiB;
  size_t need1 = base + 5 * MiB + 262144;  // wt + vtmp aliases
  int split = (ws_size >= need4) ? 4 : (ws_size >= need2) ? 2 : 1;
  (void)need1;

  hipLaunchKernelGGL(pack_w,      dim3(384),  dim3(256), 0, stream, wq, wk, wv, wt);
  hipLaunchKernelGGL(qkv_gemm,    dim3(256),  dim3(512), 0, stream, x, wt, qm, km, vtmp);
  hipLaunchKernelGGL(transpose_v, dim3(2048), dim3(256), 0, stream, vtmp, vt);
  hipLaunchKernelGGL(attn, dim3(256 * 4 * split / 4 * 1), dim3(256), 0, stream,
                     qm, km, vt, du, po, pm, pl, out, split);
  // grid above = 8 * 32 * split blocks
  if (split > 1)
    hipLaunchKernelGGL(combine, dim3(NR_), dim3(H_), 0, stream, po, pm, pl, out, split);
}

// Round 3
// 420.037 us; speedup vs baseline: 1.3753x; 1.0528x over previous
//
#include <hip/hip_runtime.h>
#include <hip/hip_bf16.h>
#include <stdint.h>
#include <stddef.h>

#define B_ 8
#define S_ 2048
#define E_ 1024
#define H_ 128
#define NR_ (B_ * S_)   // 16384 total q-rows

typedef __attribute__((ext_vector_type(8))) short short8;   // 8 x bf16 (4 VGPRs)
typedef __attribute__((ext_vector_type(4))) float f32x4;

__device__ __forceinline__ short f2bf(float f){
  uint32_t u = __builtin_bit_cast(uint32_t, f);
  u = (u + 0x7FFFu + ((u >> 16) & 1u)) >> 16;   // RNE
  return (short)(uint16_t)u;
}

#define GLOBAL_AS __attribute__((address_space(1)))
#define LDS_AS    __attribute__((address_space(3)))
__device__ __forceinline__ void async16(const void* g, void* l){
  __builtin_amdgcn_global_load_lds((const GLOBAL_AS uint32_t*)g,
                                   (LDS_AS uint32_t*)l, 16, 0, 0);
}

// ---------------------------------------------------------------------------
// wq/wk/wv [E][H] f32 -> wt [3*H][E] bf16, coalesced both sides via LDS tile.
// ---------------------------------------------------------------------------
__global__ void pack_w(const float* __restrict__ wq, const float* __restrict__ wk,
                       const float* __restrict__ wv, short* __restrict__ wt){
  __shared__ float t[32][33];
  int idx = blockIdx.x;
  int hb  = idx & 3;
  int eb  = (idx >> 2) & 31;
  int w   = idx >> 7;
  const float* src = (w == 0) ? wq : (w == 1) ? wk : wv;
  int c  = threadIdx.x & 31;
  int r0 = threadIdx.x >> 5;
#pragma unroll
  for (int i = 0; i < 4; i++){
    int r = r0 * 4 + i;
    t[r][c] = src[(size_t)(eb * 32 + r) * H_ + hb * 32 + c];
  }
  __syncthreads();
#pragma unroll
  for (int i = 0; i < 4; i++){
    int r = r0 * 4 + i;
    wt[(size_t)(w * 128 + hb * 32 + r) * E_ + eb * 32 + c] = f2bf(t[c][r]);
  }
}

// ---------------------------------------------------------------------------
// QKV GEMM v3: 1024 blocks (512 M x 2 N-halves) x 256 thr -> 4 blocks/CU so
// the stage/barrier drain of one block overlaps MFMA of another.
// Block: 32 rows x 192 cols. Wave (rg=w>>1 rows, g=w&1 cols) = 16 x 96.
// wt k-slab 32k x 192n bf16 = 12 KB staged via global_load_lds width 16.
// ---------------------------------------------------------------------------
__launch_bounds__(256)
__global__ void qkv_gemm(const float* __restrict__ x, const short* __restrict__ wt,
                         short* __restrict__ qm, short* __restrict__ km,
                         short* __restrict__ vtmp){
  __shared__ __align__(16) short slab[6144];   // [kc 4][n 192][8k] = 12288 B
  const int tid  = threadIdx.x;
  const int wave = tid >> 6;
  const int lane = tid & 63;
  const int l16  = lane & 15;
  const int quad = lane >> 4;
  const int rg   = wave >> 1;        // 0..1 row-group
  const int g    = wave & 1;         // 0..1 col-group
  const int mblk = blockIdx.x >> 1;
  const int nb2  = blockIdx.x & 1;   // which 192-col half of 384
  const int m0   = mblk * 32;

  f32x4 acc[6];
#pragma unroll
  for (int i = 0; i < 6; i++) acc[i] = (f32x4)(0.0f);

  const float* xr = x + (size_t)(m0 + rg * 16 + l16) * E_ + quad * 8;

  for (int k0 = 0; k0 < E_; k0 += 32){
    // stage 12 chunks of 1 KB, 3 per wave
#pragma unroll
    for (int i = 0; i < 3; i++){
      int c  = wave * 3 + i;          // 0..11
      int kc = c & 3;
      int nb = c >> 2;                // 0..2
      const short* gp = wt + (size_t)(nb2 * 192 + nb * 64 + lane) * E_ + k0 + kc * 8;
      async16(gp, (char*)slab + kc * 3072 + nb * 1024);
    }
    __syncthreads();

    f32x4 a0 = *(const f32x4*)(xr + k0);
    f32x4 a1 = *(const f32x4*)(xr + k0 + 4);
    short8 af;
#pragma unroll
    for (int j = 0; j < 4; j++){ af[j] = f2bf(a0[j]); af[j + 4] = f2bf(a1[j]); }

#pragma unroll
    for (int nt = 0; nt < 6; nt++){
      short8 bf = *(const short8*)((const char*)slab + quad * 3072 +
                                   (size_t)(g * 96 + nt * 16 + l16) * 16);
      acc[nt] = __builtin_amdgcn_mfma_f32_16x16x32_bf16(af, bf, acc[nt], 0, 0, 0);
    }
    __syncthreads();
  }

#pragma unroll
  for (int nt = 0; nt < 6; nt++){
    int c0  = nb2 * 192 + g * 96 + nt * 16;
    short* dst = (c0 < 128) ? qm : (c0 < 256) ? km : vtmp;
    int cin = c0 & 127;
    int row = m0 + rg * 16 + quad * 4;
#pragma unroll
    for (int r = 0; r < 4; r++)
      dst[(size_t)(row + r) * H_ + cin + l16] = f2bf(acc[nt][r]);
  }
}

// ---------------------------------------------------------------------------
// vtmp [B][S][H] -> vt [B][H][S]
// ---------------------------------------------------------------------------
__global__ void transpose_v(const short* __restrict__ v, short* __restrict__ vt){
  __shared__ short t[32][33];
  int idx = blockIdx.x;             // 2048 blocks
  int hb = idx & 3;
  int sb = (idx >> 2) & 63;
  int b  = idx >> 8;
  int s0 = sb * 32, h0 = hb * 32;
  int c  = threadIdx.x & 31;
  int r0 = threadIdx.x >> 5;
#pragma unroll
  for (int i = 0; i < 4; i++){
    int r = r0 * 4 + i;
    t[r][c] = v[((size_t)b * S_ + s0 + r) * H_ + h0 + c];
  }
  __syncthreads();
#pragma unroll
  for (int i = 0; i < 4; i++){
    int r = r0 * 4 + i;
    vt[((size_t)b * H_ + h0 + r) * S_ + s0 + c] = t[c][r];
  }
}

// ---------------------------------------------------------------------------
// Attention v3: NO online max (scores = q.k/32, |s| < 2 always -> exp2 safe),
// NO per-tile reductions (per-lane l partials, one shuffle reduce at end),
// NO __syncthreads (pbuf is per-wave; DS pipe is in-order per wave; we fence
// the compiler with sched_barrier + raw lgkmcnt(0) wait, vmcnt left in
// flight). Dropout applied in A-layout after the LDS transpose so du loads
// vectorize to dwordx4. P stored f32 in LDS (row stride 68: write 2-way
// aliasing = free, b128 read pattern == conflict-free baseline).
// ---------------------------------------------------------------------------
__launch_bounds__(256, 4)
__global__ void attn(const short* __restrict__ qm, const short* __restrict__ km,
                     const short* __restrict__ vtm, const float* __restrict__ du,
                     float* __restrict__ po, float* __restrict__ pl,
                     float* __restrict__ out, int split){
  const int wave = threadIdx.x >> 6;
  const int lane = threadIdx.x & 63;
  const int l16  = lane & 15;
  const int quad = lane >> 4;
  const int sp   = blockIdx.x & (split - 1);    // split is 1/2/4
  const int rbk  = blockIdx.x / split;
  const int b    = rbk >> 5;
  const int m0   = (rbk & 31) * 64 + wave * 16;
  const int seg  = S_ / split;

  const short* qb  = qm  + ((size_t)b * S_ + m0) * H_;
  const short* kb  = km  + (size_t)b * S_ * H_;
  const short* vb  = vtm + (size_t)b * H_ * S_;
  const float* dub = du  + ((size_t)b * S_ + m0) * S_;

  short8 qf[4];
#pragma unroll
  for (int kc = 0; kc < 4; kc++)
    qf[kc] = *(const short8*)(qb + (size_t)l16 * H_ + kc * 32 + quad * 8);

  f32x4 o[8];
#pragma unroll
  for (int ht = 0; ht < 8; ht++) o[ht] = (f32x4)(0.0f);
  float lpart[4] = {0.f, 0.f, 0.f, 0.f};

  __shared__ float pbuf[4][16][68];             // f32, per-wave slice
  float* pb = &pbuf[wave][0][0];
  const float SC2  = 0.045084220f;              // log2(e) / 32
  const float KINV = 1.0f / 0.9f;

  const int tbeg = sp * seg;
  for (int t0 = tbeg; t0 < tbeg + seg; t0 += 64){
    // ---- S = Q K^T (C-layout) ----
    f32x4 s[4];
#pragma unroll
    for (int nt = 0; nt < 4; nt++) s[nt] = (f32x4)(0.0f);
#pragma unroll
    for (int nt = 0; nt < 4; nt++){
      const short* kt = kb + (size_t)(t0 + nt * 16 + l16) * H_ + quad * 8;
#pragma unroll
      for (int kc = 0; kc < 4; kc++){
        short8 bf = *(const short8*)(kt + kc * 32);
        s[nt] = __builtin_amdgcn_mfma_f32_16x16x32_bf16(qf[kc], bf, s[nt], 0, 0, 0);
      }
    }

    // ---- p = exp2(s*SC2); accumulate per-lane l; stage to LDS ----
#pragma unroll
    for (int nt = 0; nt < 4; nt++)
#pragma unroll
      for (int r = 0; r < 4; r++){
        float p = exp2f(s[nt][r] * SC2);
        lpart[r] += p;
        pb[(quad * 4 + r) * 68 + nt * 16 + l16] = p;
      }

    __builtin_amdgcn_sched_barrier(0);
    __builtin_amdgcn_s_waitcnt(0xC07F);         // lgkmcnt(0) only
    __builtin_amdgcn_sched_barrier(0);

    // ---- read A-layout, apply dropout (vectorized du), pack bf16 ----
    const float* pr = pb + l16 * 68 + quad * 8;
    f32x4 p0 = *(const f32x4*)(pr);
    f32x4 p1 = *(const f32x4*)(pr + 4);
    f32x4 p2 = *(const f32x4*)(pr + 32);
    f32x4 p3 = *(const f32x4*)(pr + 36);
    const float* dp = dub + (size_t)l16 * S_ + t0 + quad * 8;
    f32x4 u0 = *(const f32x4*)(dp);
    f32x4 u1 = *(const f32x4*)(dp + 4);
    f32x4 u2 = *(const f32x4*)(dp + 32);
    f32x4 u3 = *(const f32x4*)(dp + 36);
    short8 pa0, pa1;
#pragma unroll
    for (int j = 0; j < 4; j++){
      pa0[j]     = f2bf((u0[j] >= 0.1f) ? p0[j] * KINV : 0.0f);
      pa0[j + 4] = f2bf((u1[j] >= 0.1f) ? p1[j] * KINV : 0.0f);
      pa1[j]     = f2bf((u2[j] >= 0.1f) ? p2[j] * KINV : 0.0f);
      pa1[j + 4] = f2bf((u3[j] >= 0.1f) ? p3[j] * KINV : 0.0f);
    }

    // ---- O += P V ----
#pragma unroll
    for (int ht = 0; ht < 8; ht++){
      const short* vp = vb + (size_t)(ht * 16 + l16) * S_ + t0 + quad * 8;
      o[ht] = __builtin_amdgcn_mfma_f32_16x16x32_bf16(pa0, *(const short8*)vp, o[ht], 0, 0, 0);
      o[ht] = __builtin_amdgcn_mfma_f32_16x16x32_bf16(pa1, *(const short8*)(vp + 32), o[ht], 0, 0, 0);
    }
    __builtin_amdgcn_sched_barrier(0);          // fence before next tile's LDS writes
  }

  // ---- one-time l reduction (within each 16-lane quad group) ----
  float lrow[4];
#pragma unroll
  for (int r = 0; r < 4; r++){
    float v = lpart[r];
    v += __shfl_xor(v, 1);
    v += __shfl_xor(v, 2);
    v += __shfl_xor(v, 4);
    v += __shfl_xor(v, 8);
    lrow[r] = v;
  }

  if (split == 1){
    float* op = out + ((size_t)b * S_ + m0) * H_;
#pragma unroll
    for (int ht = 0; ht < 8; ht++)
#pragma unroll
      for (int r = 0; r < 4; r++)
        op[(size_t)(quad * 4 + r) * H_ + ht * 16 + l16] = o[ht][r] / lrow[r];
  } else {
#pragma unroll
    for (int r = 0; r < 4; r++){
      size_t R = (size_t)b * S_ + m0 + quad * 4 + r;
#pragma unroll
      for (int ht = 0; ht < 8; ht++)
        po[((size_t)sp * NR_ + R) * H_ + ht * 16 + l16] = o[ht][r];
      if (l16 == 0) pl[(size_t)sp * NR_ + R] = lrow[r];
    }
  }
}

// ---------------------------------------------------------------------------
// Merge split partials: out = sum_s(o_s) / sum_s(l_s)   (common scale, no max)
// ---------------------------------------------------------------------------
__global__ void combine(const float* __restrict__ po, const float* __restrict__ pl,
                        float* __restrict__ out, int split){
  int row = blockIdx.x;
  int col = threadIdx.x;
  float num = 0.f, den = 0.f;
  for (int s = 0; s < split; s++){
    num += po[((size_t)s * NR_ + row) * H_ + col];
    den += pl[(size_t)s * NR_ + row];
  }
  out[(size_t)row * H_ + col] = num / den;
}

// ---------------------------------------------------------------------------
extern "C" void kernel_launch(void* const* d_in, const int* in_sizes, int n_in,
                              void* d_out, int out_size, void* d_ws, size_t ws_size,
                              hipStream_t stream){
  const float* x  = (const float*)d_in[0];
  const float* wq = (const float*)d_in[1];
  const float* wk = (const float*)d_in[2];
  const float* wv = (const float*)d_in[3];
  const float* du = (const float*)d_in[4];
  float* out = (float*)d_out;

  const size_t MiB = 1048576;
  char* ws = (char*)d_ws;
  short* qm  = (short*)(ws);                       // 4 MiB
  short* km  = (short*)(ws + 4 * MiB);             // 4 MiB
  short* vt  = (short*)(ws + 8 * MiB);             // 4 MiB
  float* pl  = (float*)(ws + 12 * MiB);            // <=512 KiB (split*64 KiB)
  float* po  = (float*)(ws + 12 * MiB + 524288);   // split*8 MiB
  // wt/vtmp alias the po region (dead before attn writes po)
  short* wt   = (short*)(ws + 12 * MiB + 524288);
  short* vtmp = (short*)(ws + 12 * MiB + 524288 + 1 * MiB);

  size_t base  = 12 * MiB + 524288;
  size_t need4 = base + 4 * 8 * MiB;
  size_t need2 = base + 2 * 8 * MiB;
  int split = (ws_size >= need4) ? 4 : (ws_size >= need2) ? 2 : 1;

  hipLaunchKernelGGL(pack_w,      dim3(384),  dim3(256), 0, stream, wq, wk, wv, wt);
  hipLaunchKernelGGL(qkv_gemm,    dim3(1024), dim3(256), 0, stream, x, wt, qm, km, vtmp);
  hipLaunchKernelGGL(transpose_v, dim3(2048), dim3(256), 0, stream, vtmp, vt);
  hipLaunchKernelGGL(attn, dim3(256 * split), dim3(256), 0, stream,
                     qm, km, vt, du, po, pl, out, split);
  if (split > 1)
    hipLaunchKernelGGL(combine, dim3(NR_), dim3(H_), 0, stream, po, pl, out, split);
}

// Round 4
// 360.219 us; speedup vs baseline: 1.6036x; 1.1661x over previous
//
#include <hip/hip_runtime.h>
#include <hip/hip_bf16.h>
#include <stdint.h>
#include <stddef.h>

#define B_ 8
#define S_ 2048
#define E_ 1024
#define H_ 128
#define NR_ (B_ * S_)   // 16384 total q-rows

typedef __attribute__((ext_vector_type(8))) short short8;   // 8 x bf16 (4 VGPRs)
typedef __attribute__((ext_vector_type(4))) float f32x4;

__device__ __forceinline__ short f2bf(float f){
  uint32_t u = __builtin_bit_cast(uint32_t, f);
  u = (u + 0x7FFFu + ((u >> 16) & 1u)) >> 16;   // RNE
  return (short)(uint16_t)u;
}

#define GLOBAL_AS __attribute__((address_space(1)))
#define LDS_AS    __attribute__((address_space(3)))
__device__ __forceinline__ void async16(const void* g, void* l){
  __builtin_amdgcn_global_load_lds((const GLOBAL_AS uint32_t*)g,
                                   (LDS_AS uint32_t*)l, 16, 0, 0);
}

// ---------------------------------------------------------------------------
// wq/wk/wv [E][H] f32 -> wt [3*H][E] bf16, coalesced both sides via LDS tile.
// ---------------------------------------------------------------------------
__global__ void pack_w(const float* __restrict__ wq, const float* __restrict__ wk,
                       const float* __restrict__ wv, short* __restrict__ wt){
  __shared__ float t[32][33];
  int idx = blockIdx.x;
  int hb  = idx & 3;
  int eb  = (idx >> 2) & 31;
  int w   = idx >> 7;
  const float* src = (w == 0) ? wq : (w == 1) ? wk : wv;
  int c  = threadIdx.x & 31;
  int r0 = threadIdx.x >> 5;
#pragma unroll
  for (int i = 0; i < 4; i++){
    int r = r0 * 4 + i;
    t[r][c] = src[(size_t)(eb * 32 + r) * H_ + hb * 32 + c];
  }
  __syncthreads();
#pragma unroll
  for (int i = 0; i < 4; i++){
    int r = r0 * 4 + i;
    wt[(size_t)(w * 128 + hb * 32 + r) * E_ + eb * 32 + c] = f2bf(t[c][r]);
  }
}

// ---------------------------------------------------------------------------
// QKV GEMM v4: grid 512 x 256 thr (2 blocks/CU). Block = 32 rows x 384 cols,
// single N-pass (x read once). Wave = 32 rows x 96 cols -> 12 MFMA : 6
// ds_read_b128 per k-step. wt slab (32k x 384n = 24 KB) double-buffered,
// staged via global_load_lds w16; prefetch issued after the barrier so the
// vmcnt drain overlaps a full compute phase.
// ---------------------------------------------------------------------------
__launch_bounds__(256)
__global__ void qkv_gemm(const float* __restrict__ x, const short* __restrict__ wt,
                         short* __restrict__ qm, short* __restrict__ km,
                         short* __restrict__ vtmp){
  __shared__ __align__(16) short slab[2][12288];   // 2 x 24 KB: [kc 4][n 384][8k]
  const int wave = threadIdx.x >> 6;
  const int lane = threadIdx.x & 63;
  const int l16  = lane & 15;
  const int quad = lane >> 4;
  const int m0   = blockIdx.x * 32;

  f32x4 acc[2][6];
#pragma unroll
  for (int a = 0; a < 2; a++)
#pragma unroll
    for (int b = 0; b < 6; b++) acc[a][b] = (f32x4)(0.0f);

  const float* xr0 = x + (size_t)(m0 + l16) * E_ + quad * 8;
  const float* xr1 = xr0 + (size_t)16 * E_;

  // stage one 24 KB slab: 24 chunks of 1 KB, 6 per wave
#define STAGE(buf, k0)                                                        \
  {                                                                           \
    _Pragma("unroll")                                                         \
    for (int i = 0; i < 6; i++){                                              \
      int c  = wave * 6 + i;                                                  \
      int kc = c & 3;                                                         \
      int nb = c >> 2;                                                        \
      const short* gp = wt + (size_t)(nb * 64 + lane) * E_ + (k0) + kc * 8;   \
      async16(gp, (char*)slab[buf] + kc * 6144 + nb * 1024);                  \
    }                                                                         \
  }

  STAGE(0, 0)
  for (int ks = 0; ks < 32; ks++){
    const int k0 = ks * 32;
    __syncthreads();
    if (ks < 31) STAGE((ks + 1) & 1, k0 + 32)

    f32x4 a00 = *(const f32x4*)(xr0 + k0);
    f32x4 a01 = *(const f32x4*)(xr0 + k0 + 4);
    f32x4 a10 = *(const f32x4*)(xr1 + k0);
    f32x4 a11 = *(const f32x4*)(xr1 + k0 + 4);
    short8 af0, af1;
#pragma unroll
    for (int j = 0; j < 4; j++){
      af0[j] = f2bf(a00[j]); af0[j + 4] = f2bf(a01[j]);
      af1[j] = f2bf(a10[j]); af1[j + 4] = f2bf(a11[j]);
    }

    const char* sb = (const char*)slab[ks & 1];
#pragma unroll
    for (int j = 0; j < 6; j++){
      int nt = wave * 6 + j;
      short8 bf = *(const short8*)(sb + quad * 6144 + (size_t)(nt * 16 + l16) * 16);
      acc[0][j] = __builtin_amdgcn_mfma_f32_16x16x32_bf16(af0, bf, acc[0][j], 0, 0, 0);
      acc[1][j] = __builtin_amdgcn_mfma_f32_16x16x32_bf16(af1, bf, acc[1][j], 0, 0, 0);
    }
  }
#undef STAGE

#pragma unroll
  for (int mt = 0; mt < 2; mt++)
#pragma unroll
    for (int j = 0; j < 6; j++){
      int c0  = wave * 96 + j * 16;
      short* dst = (c0 < 128) ? qm : (c0 < 256) ? km : vtmp;
      int cin = c0 & 127;
      int row = m0 + mt * 16 + quad * 4;
#pragma unroll
      for (int r = 0; r < 4; r++)
        dst[(size_t)(row + r) * H_ + cin + l16] = f2bf(acc[mt][j][r]);
    }
}

// ---------------------------------------------------------------------------
// vtmp [B][S][H] -> vt [B][H][S]
// ---------------------------------------------------------------------------
__global__ void transpose_v(const short* __restrict__ v, short* __restrict__ vt){
  __shared__ short t[32][33];
  int idx = blockIdx.x;             // 2048 blocks
  int hb = idx & 3;
  int sb = (idx >> 2) & 63;
  int b  = idx >> 8;
  int s0 = sb * 32, h0 = hb * 32;
  int c  = threadIdx.x & 31;
  int r0 = threadIdx.x >> 5;
#pragma unroll
  for (int i = 0; i < 4; i++){
    int r = r0 * 4 + i;
    t[r][c] = v[((size_t)b * S_ + s0 + r) * H_ + h0 + c];
  }
  __syncthreads();
#pragma unroll
  for (int i = 0; i < 4; i++){
    int r = r0 * 4 + i;
    vt[((size_t)b * H_ + h0 + r) * S_ + s0 + c] = t[c][r];
  }
}

// ---------------------------------------------------------------------------
// Attention v4: K/V tiles staged into LDS once per block via global_load_lds
// (no VGPRs held by staging -> no load serialization; was the R3 bottleneck
// at VGPR_Count=60). LDS rows are 256B/128B strided (== 0 mod 32 banks), so
// 16-B slots are XOR-swizzled by row (swizzle applied on the GLOBAL source
// address; the DMA's LDS side must stay linear). ds_reads then hit 2-way
// aliasing only (free). No online max (|s|<2), per-lane l partials, f32 pbuf
// round-trip for C->A layout, dropout vectorized in A-layout.
// ---------------------------------------------------------------------------
__launch_bounds__(256)
__global__ void attn(const short* __restrict__ qm, const short* __restrict__ km,
                     const short* __restrict__ vtm, const float* __restrict__ du,
                     float* __restrict__ po, float* __restrict__ pl,
                     float* __restrict__ out, int split){
  const int wave = threadIdx.x >> 6;
  const int lane = threadIdx.x & 63;
  const int l16  = lane & 15;
  const int quad = lane >> 4;
  const int sp   = blockIdx.x & (split - 1);    // split is 1/2/4
  const int rbk  = blockIdx.x / split;
  const int b    = rbk >> 5;
  const int m0   = (rbk & 31) * 64 + wave * 16;
  const int seg  = S_ / split;

  const short* qb  = qm  + ((size_t)b * S_ + m0) * H_;
  const short* kb  = km  + (size_t)b * S_ * H_;
  const short* vb  = vtm + (size_t)b * H_ * S_;
  const float* dub = du  + ((size_t)b * S_ + m0) * S_;

  __shared__ __align__(16) short kls[8192];     // [64 key][128 k] swizzled, 16 KB
  __shared__ __align__(16) short vls[8192];     // [128 h][64 t]  swizzled, 16 KB
  __shared__ float pbuf[4][16][68];             // per-wave P round-trip
  float* pb = &pbuf[wave][0][0];

  short8 qf[4];
#pragma unroll
  for (int kc = 0; kc < 4; kc++)
    qf[kc] = *(const short8*)(qb + (size_t)l16 * H_ + kc * 32 + quad * 8);

  f32x4 o[8];
#pragma unroll
  for (int ht = 0; ht < 8; ht++) o[ht] = (f32x4)(0.0f);
  float lpart[4] = {0.f, 0.f, 0.f, 0.f};

  const float SC2  = 0.045084220f;              // log2(e) / 32
  const float KINV = 1.0f / 0.9f;

  const int tbeg = sp * seg;
  for (int t0 = tbeg; t0 < tbeg + seg; t0 += 64){
    // ---- stage K tile: 16 chunks of 1 KB (4 rows each), 4 per wave ----
#pragma unroll
    for (int i = 0; i < 4; i++){
      int c = wave * 4 + i;
      int r = c * 4 + (lane >> 4);              // key row 0..63
      int s = lane & 15;                        // physical 16B slot
      int q = (s & 8) | ((s ^ r) & 7);          // logical slot (involution)
      async16(kb + (size_t)(t0 + r) * H_ + q * 8, (char*)kls + c * 1024);
    }
    // ---- stage V tile: 16 chunks of 1 KB (8 h-rows each), 4 per wave ----
#pragma unroll
    for (int i = 0; i < 4; i++){
      int c = wave * 4 + i;
      int r = c * 8 + (lane >> 3);              // h row 0..127
      int s = lane & 7;
      int q = (s ^ r) & 7;
      async16(vb + (size_t)r * S_ + t0 + q * 8, (char*)vls + c * 1024);
    }
    __syncthreads();

    // du loads: unique data, overlap with QK phase
    const float* dp = dub + (size_t)l16 * S_ + t0 + quad * 8;
    f32x4 u0 = *(const f32x4*)(dp);
    f32x4 u1 = *(const f32x4*)(dp + 4);
    f32x4 u2 = *(const f32x4*)(dp + 32);
    f32x4 u3 = *(const f32x4*)(dp + 36);

    // ---- S = Q K^T from LDS ----
    f32x4 s[4];
#pragma unroll
    for (int nt = 0; nt < 4; nt++) s[nt] = (f32x4)(0.0f);
#pragma unroll
    for (int nt = 0; nt < 4; nt++){
      int row = nt * 16 + l16;
#pragma unroll
      for (int kc = 0; kc < 4; kc++){
        int q  = kc * 4 + quad;
        int ph = (q & 8) | ((q ^ row) & 7);
        short8 bf = *(const short8*)((const char*)kls + row * 256 + ph * 16);
        s[nt] = __builtin_amdgcn_mfma_f32_16x16x32_bf16(qf[kc], bf, s[nt], 0, 0, 0);
      }
    }

    // ---- p = exp2(s*SC2); per-lane l; stage to pbuf (C-layout) ----
#pragma unroll
    for (int nt = 0; nt < 4; nt++)
#pragma unroll
      for (int r = 0; r < 4; r++){
        float p = exp2f(s[nt][r] * SC2);
        lpart[r] += p;
        pb[(quad * 4 + r) * 68 + nt * 16 + l16] = p;
      }

    __builtin_amdgcn_sched_barrier(0);
    __builtin_amdgcn_s_waitcnt(0xC07F);         // lgkmcnt(0) only
    __builtin_amdgcn_sched_barrier(0);

    // ---- A-layout read + dropout + pack bf16 ----
    const float* pr = pb + l16 * 68 + quad * 8;
    f32x4 p0 = *(const f32x4*)(pr);
    f32x4 p1 = *(const f32x4*)(pr + 4);
    f32x4 p2 = *(const f32x4*)(pr + 32);
    f32x4 p3 = *(const f32x4*)(pr + 36);
    short8 pa0, pa1;
#pragma unroll
    for (int j = 0; j < 4; j++){
      pa0[j]     = f2bf((u0[j] >= 0.1f) ? p0[j] * KINV : 0.0f);
      pa0[j + 4] = f2bf((u1[j] >= 0.1f) ? p1[j] * KINV : 0.0f);
      pa1[j]     = f2bf((u2[j] >= 0.1f) ? p2[j] * KINV : 0.0f);
      pa1[j + 4] = f2bf((u3[j] >= 0.1f) ? p3[j] * KINV : 0.0f);
    }

    // ---- O += P V from LDS ----
#pragma unroll
    for (int ht = 0; ht < 8; ht++){
      int row = ht * 16 + l16;
#pragma unroll
      for (int half = 0; half < 2; half++){
        int q  = half * 4 + quad;
        int ph = (q ^ row) & 7;
        short8 vf = *(const short8*)((const char*)vls + row * 128 + ph * 16);
        o[ht] = __builtin_amdgcn_mfma_f32_16x16x32_bf16(half ? pa1 : pa0, vf, o[ht], 0, 0, 0);
      }
    }
    __syncthreads();                            // protect kls/vls rewrite
  }

  float lrow[4];
#pragma unroll
  for (int r = 0; r < 4; r++){
    float v = lpart[r];
    v += __shfl_xor(v, 1);
    v += __shfl_xor(v, 2);
    v += __shfl_xor(v, 4);
    v += __shfl_xor(v, 8);
    lrow[r] = v;
  }

  if (split == 1){
    float* op = out + ((size_t)b * S_ + m0) * H_;
#pragma unroll
    for (int ht = 0; ht < 8; ht++)
#pragma unroll
      for (int r = 0; r < 4; r++)
        op[(size_t)(quad * 4 + r) * H_ + ht * 16 + l16] = o[ht][r] / lrow[r];
  } else {
#pragma unroll
    for (int r = 0; r < 4; r++){
      size_t R = (size_t)b * S_ + m0 + quad * 4 + r;
#pragma unroll
      for (int ht = 0; ht < 8; ht++)
        po[((size_t)sp * NR_ + R) * H_ + ht * 16 + l16] = o[ht][r];
      if (l16 == 0) pl[(size_t)sp * NR_ + R] = lrow[r];
    }
  }
}

// ---------------------------------------------------------------------------
// Merge split partials: out = sum_s(o_s) / sum_s(l_s)
// ---------------------------------------------------------------------------
__global__ void combine(const float* __restrict__ po, const float* __restrict__ pl,
                        float* __restrict__ out, int split){
  int row = blockIdx.x;
  int col = threadIdx.x;
  float num = 0.f, den = 0.f;
  for (int s = 0; s < split; s++){
    num += po[((size_t)s * NR_ + row) * H_ + col];
    den += pl[(size_t)s * NR_ + row];
  }
  out[(size_t)row * H_ + col] = num / den;
}

// ---------------------------------------------------------------------------
extern "C" void kernel_launch(void* const* d_in, const int* in_sizes, int n_in,
                              void* d_out, int out_size, void* d_ws, size_t ws_size,
                              hipStream_t stream){
  const float* x  = (const float*)d_in[0];
  const float* wq = (const float*)d_in[1];
  const float* wk = (const float*)d_in[2];
  const float* wv = (const float*)d_in[3];
  const float* du = (const float*)d_in[4];
  float* out = (float*)d_out;

  const size_t MiB = 1048576;
  char* ws = (char*)d_ws;
  short* qm  = (short*)(ws);                       // 4 MiB
  short* km  = (short*)(ws + 4 * MiB);             // 4 MiB
  short* vt  = (short*)(ws + 8 * MiB);             // 4 MiB
  float* pl  = (float*)(ws + 12 * MiB);            // <=512 KiB
  float* po  = (float*)(ws + 12 * MiB + 524288);   // split*8 MiB
  // wt/vtmp alias the po region (dead before attn writes po)
  short* wt   = (short*)(ws + 12 * MiB + 524288);
  short* vtmp = (short*)(ws + 12 * MiB + 524288 + 1 * MiB);

  size_t base  = 12 * MiB + 524288;
  size_t need4 = base + 4 * 8 * MiB;
  size_t need2 = base + 2 * 8 * MiB;
  int split = (ws_size >= need4) ? 4 : (ws_size >= need2) ? 2 : 1;

  hipLaunchKernelGGL(pack_w,      dim3(384),  dim3(256), 0, stream, wq, wk, wv, wt);
  hipLaunchKernelGGL(qkv_gemm,    dim3(512),  dim3(256), 0, stream, x, wt, qm, km, vtmp);
  hipLaunchKernelGGL(transpose_v, dim3(2048), dim3(256), 0, stream, vtmp, vt);
  hipLaunchKernelGGL(attn, dim3(256 * split), dim3(256), 0, stream,
                     qm, km, vt, du, po, pl, out, split);
  if (split > 1)
    hipLaunchKernelGGL(combine, dim3(NR_), dim3(H_), 0, stream, po, pl, out, split);
}

// Round 5
// 302.146 us; speedup vs baseline: 1.9119x; 1.1922x over previous
//
#include <hip/hip_runtime.h>
#include <hip/hip_bf16.h>
#include <stdint.h>
#include <stddef.h>

#define B_ 8
#define S_ 2048
#define E_ 1024
#define H_ 128
#define NR_ (B_ * S_)   // 16384 total q-rows

typedef __attribute__((ext_vector_type(8))) short short8;   // 8 x bf16 (4 VGPRs)
typedef __attribute__((ext_vector_type(4))) float f32x4;

__device__ __forceinline__ short f2bf(float f){
  uint32_t u = __builtin_bit_cast(uint32_t, f);
  u = (u + 0x7FFFu + ((u >> 16) & 1u)) >> 16;   // RNE
  return (short)(uint16_t)u;
}

#define GLOBAL_AS __attribute__((address_space(1)))
#define LDS_AS    __attribute__((address_space(3)))
__device__ __forceinline__ void async16(const void* g, void* l){
  __builtin_amdgcn_global_load_lds((const GLOBAL_AS uint32_t*)g,
                                   (LDS_AS uint32_t*)l, 16, 0, 0);
}

// ---------------------------------------------------------------------------
// x [B*S][E] f32 -> xb bf16 (so the GEMM can DMA-stage A tiles)
// ---------------------------------------------------------------------------
__global__ void cast_x(const float* __restrict__ x, short* __restrict__ xb){
  size_t i = ((size_t)blockIdx.x * 256 + threadIdx.x) * 8;   // grid 8192
  f32x4 a = *(const f32x4*)(x + i);
  f32x4 b = *(const f32x4*)(x + i + 4);
  short8 o;
#pragma unroll
  for (int j = 0; j < 4; j++){ o[j] = f2bf(a[j]); o[j + 4] = f2bf(b[j]); }
  *(short8*)(xb + i) = o;
}

// ---------------------------------------------------------------------------
// wq/wk/wv [E][H] f32 -> wt [3*H][E] bf16, coalesced both sides via LDS tile.
// ---------------------------------------------------------------------------
__global__ void pack_w(const float* __restrict__ wq, const float* __restrict__ wk,
                       const float* __restrict__ wv, short* __restrict__ wt){
  __shared__ float t[32][33];
  int idx = blockIdx.x;
  int hb  = idx & 3;
  int eb  = (idx >> 2) & 31;
  int w   = idx >> 7;
  const float* src = (w == 0) ? wq : (w == 1) ? wk : wv;
  int c  = threadIdx.x & 31;
  int r0 = threadIdx.x >> 5;
#pragma unroll
  for (int i = 0; i < 4; i++){
    int r = r0 * 4 + i;
    t[r][c] = src[(size_t)(eb * 32 + r) * H_ + hb * 32 + c];
  }
  __syncthreads();
#pragma unroll
  for (int i = 0; i < 4; i++){
    int r = r0 * 4 + i;
    wt[(size_t)(w * 128 + hb * 32 + r) * E_ + eb * 32 + c] = f2bf(t[c][r]);
  }
}

// ---------------------------------------------------------------------------
// QKV GEMM v5 — m97-pattern 128x128 tile. grid dim3(3, 128): y = M-block,
// x = N-block (0->q, 1->k, 2->v). 4 waves; wave w owns rows (w&1)*64,
// cols (w>>1)*64: 4x4 acc tiles of 16x16 -> 64 MFMA per block k-step.
// A (xb) and B (wt) tiles [128][32] bf16 DMA-staged, double-buffered.
// 16-B LDS slots XOR-swizzled by (row>>1)&3 applied on the GLOBAL source
// address (DMA LDS side must stay linear); frag ds_read_b128 then lands
// 2 lanes/bank (free, m136).
// ---------------------------------------------------------------------------
__launch_bounds__(256)
__global__ void qkv_gemm(const short* __restrict__ xb, const short* __restrict__ wt,
                         short* __restrict__ qm, short* __restrict__ km,
                         short* __restrict__ vtmp){
  __shared__ __align__(16) short abuf[2][4096];   // [128 m][4 slot][8 k] = 8 KB
  __shared__ __align__(16) short bbuf[2][4096];   // [128 n][4 slot][8 k]
  const int wave = threadIdx.x >> 6;
  const int lane = threadIdx.x & 63;
  const int l16  = lane & 15;
  const int quad = lane >> 4;
  const int nb   = blockIdx.x;        // 0..2
  const int m0   = blockIdx.y * 128;
  const int n0   = nb * 128;

  f32x4 acc[4][4];
#pragma unroll
  for (int i = 0; i < 4; i++)
#pragma unroll
    for (int j = 0; j < 4; j++) acc[i][j] = (f32x4)(0.0f);

  // stage one k-slice: A 8 chunks + B 8 chunks of 1 KB; 4 per wave.
  // chunk c covers rows c*16..c*16+15; lane l -> row c*16+(l>>2), slot l&3,
  // holding logical k-chunk q = (slot ^ ((row>>1)&3)) & 3.
#define STAGE(buf, k0)                                                        \
  {                                                                           \
    _Pragma("unroll")                                                         \
    for (int i = 0; i < 2; i++){                                              \
      int c = wave * 2 + i;                                                   \
      int r = c * 16 + (lane >> 2);                                           \
      int q = ((lane & 3) ^ ((r >> 1) & 3)) & 3;                              \
      async16(xb + (size_t)(m0 + r) * E_ + (k0) + q * 8,                      \
              (char*)abuf[buf] + c * 1024);                                   \
      async16(wt + (size_t)(n0 + r) * E_ + (k0) + q * 8,                      \
              (char*)bbuf[buf] + c * 1024);                                   \
    }                                                                         \
  }

  STAGE(0, 0)
  for (int ks = 0; ks < 32; ks++){
    const int k0 = ks * 32;
    __syncthreads();
    if (ks < 31) STAGE((ks + 1) & 1, k0 + 32)

    const short* ab = abuf[ks & 1];
    const short* bb = bbuf[ks & 1];
    short8 af[4], bf[4];
#pragma unroll
    for (int t = 0; t < 4; t++){
      int ra = (wave & 1) * 64 + t * 16 + l16;
      int pa = (quad ^ ((ra >> 1) & 3)) & 3;
      af[t] = *(const short8*)(ab + ra * 32 + pa * 8);
      int rb = (wave >> 1) * 64 + t * 16 + l16;
      int pb = (quad ^ ((rb >> 1) & 3)) & 3;
      bf[t] = *(const short8*)(bb + rb * 32 + pb * 8);
    }
#pragma unroll
    for (int mt = 0; mt < 4; mt++)
#pragma unroll
      for (int nt = 0; nt < 4; nt++)
        acc[mt][nt] = __builtin_amdgcn_mfma_f32_16x16x32_bf16(af[mt], bf[nt], acc[mt][nt], 0, 0, 0);
  }
#undef STAGE

  short* dst = (nb == 0) ? qm : (nb == 1) ? km : vtmp;
#pragma unroll
  for (int mt = 0; mt < 4; mt++)
#pragma unroll
    for (int nt = 0; nt < 4; nt++){
      int row = m0 + (wave & 1) * 64 + mt * 16 + quad * 4;
      int col = (wave >> 1) * 64 + nt * 16 + l16;
#pragma unroll
      for (int r = 0; r < 4; r++)
        dst[(size_t)(row + r) * H_ + col] = f2bf(acc[mt][nt][r]);
    }
}

// ---------------------------------------------------------------------------
// vtmp [B][S][H] -> vt [B][H][S]
// ---------------------------------------------------------------------------
__global__ void transpose_v(const short* __restrict__ v, short* __restrict__ vt){
  __shared__ short t[32][33];
  int idx = blockIdx.x;             // 2048 blocks
  int hb = idx & 3;
  int sb = (idx >> 2) & 63;
  int b  = idx >> 8;
  int s0 = sb * 32, h0 = hb * 32;
  int c  = threadIdx.x & 31;
  int r0 = threadIdx.x >> 5;
#pragma unroll
  for (int i = 0; i < 4; i++){
    int r = r0 * 4 + i;
    t[r][c] = v[((size_t)b * S_ + s0 + r) * H_ + h0 + c];
  }
  __syncthreads();
#pragma unroll
  for (int i = 0; i < 4; i++){
    int r = r0 * 4 + i;
    vt[((size_t)b * H_ + h0 + r) * S_ + s0 + c] = t[c][r];
  }
}

// ---------------------------------------------------------------------------
// Attention v4 (unchanged from R4): K/V LDS-staged via global_load_lds with
// XOR-swizzled source slots; no online max (|s|<2); per-lane l partials;
// f32 pbuf C->A round-trip; vectorized dropout.
// ---------------------------------------------------------------------------
__launch_bounds__(256)
__global__ void attn(const short* __restrict__ qm, const short* __restrict__ km,
                     const short* __restrict__ vtm, const float* __restrict__ du,
                     float* __restrict__ po, float* __restrict__ pl,
                     float* __restrict__ out, int split){
  const int wave = threadIdx.x >> 6;
  const int lane = threadIdx.x & 63;
  const int l16  = lane & 15;
  const int quad = lane >> 4;
  const int sp   = blockIdx.x & (split - 1);    // split is 1/2/4
  const int rbk  = blockIdx.x / split;
  const int b    = rbk >> 5;
  const int m0   = (rbk & 31) * 64 + wave * 16;
  const int seg  = S_ / split;

  const short* qb  = qm  + ((size_t)b * S_ + m0) * H_;
  const short* kb  = km  + (size_t)b * S_ * H_;
  const short* vb  = vtm + (size_t)b * H_ * S_;
  const float* dub = du  + ((size_t)b * S_ + m0) * S_;

  __shared__ __align__(16) short kls[8192];     // [64 key][128 k] swizzled
  __shared__ __align__(16) short vls[8192];     // [128 h][64 t]  swizzled
  __shared__ float pbuf[4][16][68];
  float* pb = &pbuf[wave][0][0];

  short8 qf[4];
#pragma unroll
  for (int kc = 0; kc < 4; kc++)
    qf[kc] = *(const short8*)(qb + (size_t)l16 * H_ + kc * 32 + quad * 8);

  f32x4 o[8];
#pragma unroll
  for (int ht = 0; ht < 8; ht++) o[ht] = (f32x4)(0.0f);
  float lpart[4] = {0.f, 0.f, 0.f, 0.f};

  const float SC2  = 0.045084220f;              // log2(e) / 32
  const float KINV = 1.0f / 0.9f;

  const int tbeg = sp * seg;
  for (int t0 = tbeg; t0 < tbeg + seg; t0 += 64){
#pragma unroll
    for (int i = 0; i < 4; i++){
      int c = wave * 4 + i;
      int r = c * 4 + (lane >> 4);
      int s = lane & 15;
      int q = (s & 8) | ((s ^ r) & 7);
      async16(kb + (size_t)(t0 + r) * H_ + q * 8, (char*)kls + c * 1024);
    }
#pragma unroll
    for (int i = 0; i < 4; i++){
      int c = wave * 4 + i;
      int r = c * 8 + (lane >> 3);
      int s = lane & 7;
      int q = (s ^ r) & 7;
      async16(vb + (size_t)r * S_ + t0 + q * 8, (char*)vls + c * 1024);
    }
    __syncthreads();

    const float* dp = dub + (size_t)l16 * S_ + t0 + quad * 8;
    f32x4 u0 = *(const f32x4*)(dp);
    f32x4 u1 = *(const f32x4*)(dp + 4);
    f32x4 u2 = *(const f32x4*)(dp + 32);
    f32x4 u3 = *(const f32x4*)(dp + 36);

    f32x4 s[4];
#pragma unroll
    for (int nt = 0; nt < 4; nt++) s[nt] = (f32x4)(0.0f);
#pragma unroll
    for (int nt = 0; nt < 4; nt++){
      int row = nt * 16 + l16;
#pragma unroll
      for (int kc = 0; kc < 4; kc++){
        int q  = kc * 4 + quad;
        int ph = (q & 8) | ((q ^ row) & 7);
        short8 bf = *(const short8*)((const char*)kls + row * 256 + ph * 16);
        s[nt] = __builtin_amdgcn_mfma_f32_16x16x32_bf16(qf[kc], bf, s[nt], 0, 0, 0);
      }
    }

#pragma unroll
    for (int nt = 0; nt < 4; nt++)
#pragma unroll
      for (int r = 0; r < 4; r++){
        float p = exp2f(s[nt][r] * SC2);
        lpart[r] += p;
        pb[(quad * 4 + r) * 68 + nt * 16 + l16] = p;
      }

    __builtin_amdgcn_sched_barrier(0);
    __builtin_amdgcn_s_waitcnt(0xC07F);         // lgkmcnt(0) only
    __builtin_amdgcn_sched_barrier(0);

    const float* pr = pb + l16 * 68 + quad * 8;
    f32x4 p0 = *(const f32x4*)(pr);
    f32x4 p1 = *(const f32x4*)(pr + 4);
    f32x4 p2 = *(const f32x4*)(pr + 32);
    f32x4 p3 = *(const f32x4*)(pr + 36);
    short8 pa0, pa1;
#pragma unroll
    for (int j = 0; j < 4; j++){
      pa0[j]     = f2bf((u0[j] >= 0.1f) ? p0[j] * KINV : 0.0f);
      pa0[j + 4] = f2bf((u1[j] >= 0.1f) ? p1[j] * KINV : 0.0f);
      pa1[j]     = f2bf((u2[j] >= 0.1f) ? p2[j] * KINV : 0.0f);
      pa1[j + 4] = f2bf((u3[j] >= 0.1f) ? p3[j] * KINV : 0.0f);
    }

#pragma unroll
    for (int ht = 0; ht < 8; ht++){
      int row = ht * 16 + l16;
#pragma unroll
      for (int half = 0; half < 2; half++){
        int q  = half * 4 + quad;
        int ph = (q ^ row) & 7;
        short8 vf = *(const short8*)((const char*)vls + row * 128 + ph * 16);
        o[ht] = __builtin_amdgcn_mfma_f32_16x16x32_bf16(half ? pa1 : pa0, vf, o[ht], 0, 0, 0);
      }
    }
    __syncthreads();
  }

  float lrow[4];
#pragma unroll
  for (int r = 0; r < 4; r++){
    float v = lpart[r];
    v += __shfl_xor(v, 1);
    v += __shfl_xor(v, 2);
    v += __shfl_xor(v, 4);
    v += __shfl_xor(v, 8);
    lrow[r] = v;
  }

  if (split == 1){
    float* op = out + ((size_t)b * S_ + m0) * H_;
#pragma unroll
    for (int ht = 0; ht < 8; ht++)
#pragma unroll
      for (int r = 0; r < 4; r++)
        op[(size_t)(quad * 4 + r) * H_ + ht * 16 + l16] = o[ht][r] / lrow[r];
  } else {
#pragma unroll
    for (int r = 0; r < 4; r++){
      size_t R = (size_t)b * S_ + m0 + quad * 4 + r;
#pragma unroll
      for (int ht = 0; ht < 8; ht++)
        po[((size_t)sp * NR_ + R) * H_ + ht * 16 + l16] = o[ht][r];
      if (l16 == 0) pl[(size_t)sp * NR_ + R] = lrow[r];
    }
  }
}

// ---------------------------------------------------------------------------
__global__ void combine(const float* __restrict__ po, const float* __restrict__ pl,
                        float* __restrict__ out, int split){
  int row = blockIdx.x;
  int col = threadIdx.x;
  float num = 0.f, den = 0.f;
  for (int s = 0; s < split; s++){
    num += po[((size_t)s * NR_ + row) * H_ + col];
    den += pl[(size_t)s * NR_ + row];
  }
  out[(size_t)row * H_ + col] = num / den;
}

// ---------------------------------------------------------------------------
extern "C" void kernel_launch(void* const* d_in, const int* in_sizes, int n_in,
                              void* d_out, int out_size, void* d_ws, size_t ws_size,
                              hipStream_t stream){
  const float* x  = (const float*)d_in[0];
  const float* wq = (const float*)d_in[1];
  const float* wk = (const float*)d_in[2];
  const float* wv = (const float*)d_in[3];
  const float* du = (const float*)d_in[4];
  float* out = (float*)d_out;

  const size_t MiB = 1048576;
  char* ws = (char*)d_ws;
  short* qm = (short*)(ws);                      // 4 MiB
  short* km = (short*)(ws + 4 * MiB);            // 4 MiB
  short* vt = (short*)(ws + 8 * MiB);            // 4 MiB

  // Tiered layout. Proven floor from earlier rounds: ws_size >= 44.5 MiB.
  // A: split4 : pl@12M, po@12.5M (32M, wt/vtmp alias head), xb@44.5M -> 76.5M
  // B: split2 : same with po 16M, xb@28.5M                          -> 60.5M
  // C: split1 : xb@8M..40M overlapping vt (vt written after qkv reads xb),
  //             wt@40M, vtmp@40.75M                                 -> 44.75M
  size_t needA = (size_t)(76.5 * MiB);
  size_t needB = (size_t)(60.5 * MiB);
  int split;
  float *pl = nullptr, *po = nullptr;
  short *wt, *vtmp, *xb;
  if (ws_size >= needA){
    split = 4;
    pl   = (float*)(ws + 12 * MiB);
    po   = (float*)(ws + 12 * MiB + 524288);
    wt   = (short*)(ws + 12 * MiB + 524288);
    vtmp = (short*)(ws + 12 * MiB + 524288 + 1 * MiB);
    xb   = (short*)(ws + 12 * MiB + 524288 + 32 * MiB);
  } else if (ws_size >= needB){
    split = 2;
    pl   = (float*)(ws + 12 * MiB);
    po   = (float*)(ws + 12 * MiB + 524288);
    wt   = (short*)(ws + 12 * MiB + 524288);
    vtmp = (short*)(ws + 12 * MiB + 524288 + 1 * MiB);
    xb   = (short*)(ws + 12 * MiB + 524288 + 16 * MiB);
  } else {
    split = 1;
    xb   = (short*)(ws + 8 * MiB);               // overlaps vt; xb dead first
    wt   = (short*)(ws + 40 * MiB);
    vtmp = (short*)(ws + 40 * MiB + 786432);
  }

  hipLaunchKernelGGL(cast_x,      dim3(8192),      dim3(256), 0, stream, x, xb);
  hipLaunchKernelGGL(pack_w,      dim3(384),       dim3(256), 0, stream, wq, wk, wv, wt);
  hipLaunchKernelGGL(qkv_gemm,    dim3(3, 128),    dim3(256), 0, stream, xb, wt, qm, km, vtmp);
  hipLaunchKernelGGL(transpose_v, dim3(2048),      dim3(256), 0, stream, vtmp, vt);
  hipLaunchKernelGGL(attn,        dim3(256 * split), dim3(256), 0, stream,
                     qm, km, vt, du, po, pl, out, split);
  if (split > 1)
    hipLaunchKernelGGL(combine, dim3(NR_), dim3(H_), 0, stream, po, pl, out, split);
}

// Round 7
// 290.727 us; speedup vs baseline: 1.9870x; 1.0393x over previous
//
#include <hip/hip_runtime.h>
#include <hip/hip_bf16.h>
#include <stdint.h>
#include <stddef.h>

#define B_ 8
#define S_ 2048
#define E_ 1024
#define H_ 128
#define NR_ (B_ * S_)   // 16384 total q-rows

typedef __attribute__((ext_vector_type(8))) short short8;   // 8 x bf16 (4 VGPRs)
typedef __attribute__((ext_vector_type(4))) short short4v;
typedef __attribute__((ext_vector_type(4))) float f32x4;

__device__ __forceinline__ short f2bf(float f){
  uint32_t u = __builtin_bit_cast(uint32_t, f);
  u = (u + 0x7FFFu + ((u >> 16) & 1u)) >> 16;   // RNE
  return (short)(uint16_t)u;
}

#define GLOBAL_AS __attribute__((address_space(1)))
#define LDS_AS    __attribute__((address_space(3)))
__device__ __forceinline__ void async16(const void* g, void* l){
  __builtin_amdgcn_global_load_lds((const GLOBAL_AS uint32_t*)g,
                                   (LDS_AS uint32_t*)l, 16, 0, 0);
}

// ---------------------------------------------------------------------------
// prep = cast_x (blocks 0..8191) + pack_w (blocks 8192..8575), fused to cut
// a dispatch. cast: x f32 -> xb bf16. pack: w [E][H] f32 -> wt [3H][E] bf16.
// ---------------------------------------------------------------------------
__global__ void prep(const float* __restrict__ x, const float* __restrict__ wq,
                     const float* __restrict__ wk, const float* __restrict__ wv,
                     short* __restrict__ xb, short* __restrict__ wt){
  __shared__ float t[32][33];
  int bid = blockIdx.x;
  if (bid < 8192){
    size_t i = ((size_t)bid * 256 + threadIdx.x) * 8;
    f32x4 a = *(const f32x4*)(x + i);
    f32x4 b = *(const f32x4*)(x + i + 4);
    short8 o;
#pragma unroll
    for (int j = 0; j < 4; j++){ o[j] = f2bf(a[j]); o[j + 4] = f2bf(b[j]); }
    *(short8*)(xb + i) = o;
  } else {
    int idx = bid - 8192;
    int hb  = idx & 3;
    int eb  = (idx >> 2) & 31;
    int w   = idx >> 7;
    const float* src = (w == 0) ? wq : (w == 1) ? wk : wv;
    int c  = threadIdx.x & 31;
    int r0 = threadIdx.x >> 5;
#pragma unroll
    for (int i = 0; i < 4; i++){
      int r = r0 * 4 + i;
      t[r][c] = src[(size_t)(eb * 32 + r) * H_ + hb * 32 + c];
    }
    __syncthreads();
#pragma unroll
    for (int i = 0; i < 4; i++){
      int r = r0 * 4 + i;
      wt[(size_t)(w * 128 + hb * 32 + r) * E_ + eb * 32 + c] = f2bf(t[c][r]);
    }
  }
}

// ---------------------------------------------------------------------------
// QKV GEMM v6 — m97-pattern 128x128 tile, with the V transpose FUSED into the
// nb==2 epilogue (acc -> LDS [h][s] -> coalesced vt[b][h][s] stores), reusing
// the stage buffers as a 128x132 bf16 overlay. LDS pointers computed by
// offset arithmetic (NO pointer arrays into LDS: addrspacecast-in-initializer
// fails to compile on gfx950).
// ---------------------------------------------------------------------------
__launch_bounds__(256)
__global__ void qkv_gemm(const short* __restrict__ xb, const short* __restrict__ wt,
                         short* __restrict__ qm, short* __restrict__ km,
                         short* __restrict__ vt){
  __shared__ __align__(16) short smem[16896];   // 33792 B: stage 32 KB | vtile 33 KB
  // layout: abuf = smem + buf*4096, bbuf = smem + 8192 + buf*4096
  const int wave = threadIdx.x >> 6;
  const int lane = threadIdx.x & 63;
  const int l16  = lane & 15;
  const int quad = lane >> 4;
  const int nb   = blockIdx.x;        // 0..2  (q,k,v)
  const int m0   = blockIdx.y * 128;
  const int n0   = nb * 128;

  f32x4 acc[4][4];
#pragma unroll
  for (int i = 0; i < 4; i++)
#pragma unroll
    for (int j = 0; j < 4; j++) acc[i][j] = (f32x4)(0.0f);

#define STAGE(buf, k0)                                                        \
  {                                                                           \
    _Pragma("unroll")                                                         \
    for (int i = 0; i < 2; i++){                                              \
      int c = wave * 2 + i;                                                   \
      int r = c * 16 + (lane >> 2);                                           \
      int q = ((lane & 3) ^ ((r >> 1) & 3)) & 3;                              \
      async16(xb + (size_t)(m0 + r) * E_ + (k0) + q * 8,                      \
              (char*)(smem + (buf) * 4096) + c * 1024);                       \
      async16(wt + (size_t)(n0 + r) * E_ + (k0) + q * 8,                      \
              (char*)(smem + 8192 + (buf) * 4096) + c * 1024);                \
    }                                                                         \
  }

  STAGE(0, 0)
  for (int ks = 0; ks < 32; ks++){
    const int k0 = ks * 32;
    __syncthreads();
    if (ks < 31) STAGE((ks + 1) & 1, k0 + 32)

    const short* a = smem + (ks & 1) * 4096;
    const short* b = smem + 8192 + (ks & 1) * 4096;
    short8 af[4], bf[4];
#pragma unroll
    for (int t = 0; t < 4; t++){
      int ra = (wave & 1) * 64 + t * 16 + l16;
      int pa = (quad ^ ((ra >> 1) & 3)) & 3;
      af[t] = *(const short8*)(a + ra * 32 + pa * 8);
      int rb = (wave >> 1) * 64 + t * 16 + l16;
      int pb = (quad ^ ((rb >> 1) & 3)) & 3;
      bf[t] = *(const short8*)(b + rb * 32 + pb * 8);
    }
#pragma unroll
    for (int mt = 0; mt < 4; mt++)
#pragma unroll
      for (int nt = 0; nt < 4; nt++)
        acc[mt][nt] = __builtin_amdgcn_mfma_f32_16x16x32_bf16(af[mt], bf[nt], acc[mt][nt], 0, 0, 0);
  }
#undef STAGE

  if (nb != 2){
    short* dst = (nb == 0) ? qm : km;
#pragma unroll
    for (int mt = 0; mt < 4; mt++)
#pragma unroll
      for (int nt = 0; nt < 4; nt++){
        int row = m0 + (wave & 1) * 64 + mt * 16 + quad * 4;
        int col = (wave >> 1) * 64 + nt * 16 + l16;
#pragma unroll
        for (int r = 0; r < 4; r++)
          dst[(size_t)(row + r) * H_ + col] = f2bf(acc[mt][nt][r]);
      }
  } else {
    __syncthreads();                            // stage bufs dead; reuse as vtile
#pragma unroll
    for (int mt = 0; mt < 4; mt++)
#pragma unroll
      for (int nt = 0; nt < 4; nt++){
        int scol = (wave & 1) * 64 + mt * 16 + quad * 4;   // s within tile
        int hrow = (wave >> 1) * 64 + nt * 16 + l16;       // h
        short4v t4;
#pragma unroll
        for (int r = 0; r < 4; r++) t4[r] = f2bf(acc[mt][nt][r]);
        *(short4v*)(smem + hrow * 132 + scol) = t4;
      }
    __syncthreads();
    int h   = threadIdx.x >> 1;
    int s0  = (threadIdx.x & 1) * 64;
    int bb_ = m0 >> 11;                         // batch
    short* dstv = vt + ((size_t)bb_ * H_ + h) * S_ + (m0 & (S_ - 1)) + s0;
    const short* srcv = smem + h * 132 + s0;
#pragma unroll
    for (int i = 0; i < 8; i++)
      *(short8*)(dstv + i * 8) = *(const short8*)(srcv + i * 8);
  }
}

// ---------------------------------------------------------------------------
// Attention v5: 512 threads (8 waves), 128 q-rows/block -> K/V staging
// amortized 2x vs v4. bf16 pbuf (18 KB) with the dropout 1/0.9 scale folded
// into the o-epilogue so the P-pack is a pure bf16 select. LDS 50 KB.
// No online max (|s|<2); per-lane l partials; XOR-swizzled DMA staging.
// ---------------------------------------------------------------------------
__launch_bounds__(512)
__global__ void attn(const short* __restrict__ qm, const short* __restrict__ km,
                     const short* __restrict__ vtm, const float* __restrict__ du,
                     float* __restrict__ po, float* __restrict__ pl,
                     float* __restrict__ out, int split){
  const int wave = threadIdx.x >> 6;
  const int lane = threadIdx.x & 63;
  const int l16  = lane & 15;
  const int quad = lane >> 4;
  const int sp   = blockIdx.x & (split - 1);    // split is 1/2/4
  const int rbk  = blockIdx.x / split;
  const int b    = rbk >> 4;                    // 16 row-blocks per batch
  const int m0   = (rbk & 15) * 128 + wave * 16;
  const int seg  = S_ / split;

  const short* qb  = qm  + ((size_t)b * S_ + m0) * H_;
  const short* kb  = km  + (size_t)b * S_ * H_;
  const short* vb  = vtm + (size_t)b * H_ * S_;
  const float* dub = du  + ((size_t)b * S_ + m0) * S_;

  __shared__ __align__(16) short kls[8192];     // [64 key][128 k] swizzled
  __shared__ __align__(16) short vls[8192];     // [128 h][64 t]  swizzled
  __shared__ short pbuf[8][16][72];             // bf16 P round-trip, per-wave
  short* pb = &pbuf[wave][0][0];

  short8 qf[4];
#pragma unroll
  for (int kc = 0; kc < 4; kc++)
    qf[kc] = *(const short8*)(qb + (size_t)l16 * H_ + kc * 32 + quad * 8);

  f32x4 o[8];
#pragma unroll
  for (int ht = 0; ht < 8; ht++) o[ht] = (f32x4)(0.0f);
  float lpart[4] = {0.f, 0.f, 0.f, 0.f};

  const float SC2  = 0.045084220f;              // log2(e) / 32
  const float KINV = 1.0f / 0.9f;

  const int tbeg = sp * seg;
  for (int t0 = tbeg; t0 < tbeg + seg; t0 += 64){
    // ---- stage K (16 chunks) + V (16 chunks), 2+2 per wave ----
#pragma unroll
    for (int i = 0; i < 2; i++){
      int c = wave * 2 + i;
      int r = c * 4 + (lane >> 4);
      int s = lane & 15;
      int q = (s & 8) | ((s ^ r) & 7);
      async16(kb + (size_t)(t0 + r) * H_ + q * 8, (char*)kls + c * 1024);
    }
#pragma unroll
    for (int i = 0; i < 2; i++){
      int c = wave * 2 + i;
      int r = c * 8 + (lane >> 3);
      int s = lane & 7;
      int q = (s ^ r) & 7;
      async16(vb + (size_t)r * S_ + t0 + q * 8, (char*)vls + c * 1024);
    }
    __syncthreads();

    // du loads (unique data) issued early to overlap QK phase
    const float* dp = dub + (size_t)l16 * S_ + t0 + quad * 8;
    f32x4 u0 = *(const f32x4*)(dp);
    f32x4 u1 = *(const f32x4*)(dp + 4);
    f32x4 u2 = *(const f32x4*)(dp + 32);
    f32x4 u3 = *(const f32x4*)(dp + 36);

    // ---- S = Q K^T ----
    f32x4 s[4];
#pragma unroll
    for (int nt = 0; nt < 4; nt++) s[nt] = (f32x4)(0.0f);
#pragma unroll
    for (int nt = 0; nt < 4; nt++){
      int row = nt * 16 + l16;
#pragma unroll
      for (int kc = 0; kc < 4; kc++){
        int q  = kc * 4 + quad;
        int ph = (q & 8) | ((q ^ row) & 7);
        short8 bf = *(const short8*)((const char*)kls + row * 256 + ph * 16);
        s[nt] = __builtin_amdgcn_mfma_f32_16x16x32_bf16(qf[kc], bf, s[nt], 0, 0, 0);
      }
    }

    // ---- p = exp2(s*SC2); per-lane l; stage bf16 P to pbuf (C-layout) ----
#pragma unroll
    for (int nt = 0; nt < 4; nt++)
#pragma unroll
      for (int r = 0; r < 4; r++){
        float p = exp2f(s[nt][r] * SC2);
        lpart[r] += p;
        pb[(quad * 4 + r) * 72 + nt * 16 + l16] = f2bf(p);
      }

    __builtin_amdgcn_sched_barrier(0);
    __builtin_amdgcn_s_waitcnt(0xC07F);         // lgkmcnt(0) only
    __builtin_amdgcn_sched_barrier(0);

    // ---- A-layout read + dropout select (scale folded to epilogue) ----
    const short* pr = pb + l16 * 72 + quad * 8;
    short8 pb0 = *(const short8*)(pr);
    short8 pb1 = *(const short8*)(pr + 32);
    short8 pa0, pa1;
#pragma unroll
    for (int j = 0; j < 4; j++){
      pa0[j]     = (u0[j] >= 0.1f) ? pb0[j]     : (short)0;
      pa0[j + 4] = (u1[j] >= 0.1f) ? pb0[j + 4] : (short)0;
      pa1[j]     = (u2[j] >= 0.1f) ? pb1[j]     : (short)0;
      pa1[j + 4] = (u3[j] >= 0.1f) ? pb1[j + 4] : (short)0;
    }

    // ---- O += P V ----
#pragma unroll
    for (int ht = 0; ht < 8; ht++){
      int row = ht * 16 + l16;
#pragma unroll
      for (int half = 0; half < 2; half++){
        int q  = half * 4 + quad;
        int ph = (q ^ row) & 7;
        short8 vf = *(const short8*)((const char*)vls + row * 128 + ph * 16);
        o[ht] = __builtin_amdgcn_mfma_f32_16x16x32_bf16(half ? pa1 : pa0, vf, o[ht], 0, 0, 0);
      }
    }
    __syncthreads();                            // protect kls/vls rewrite
  }

  float lrow[4];
#pragma unroll
  for (int r = 0; r < 4; r++){
    float v = lpart[r];
    v += __shfl_xor(v, 1);
    v += __shfl_xor(v, 2);
    v += __shfl_xor(v, 4);
    v += __shfl_xor(v, 8);
    lrow[r] = v;
  }

  if (split == 1){
    float* op = out + ((size_t)b * S_ + m0) * H_;
#pragma unroll
    for (int ht = 0; ht < 8; ht++)
#pragma unroll
      for (int r = 0; r < 4; r++)
        op[(size_t)(quad * 4 + r) * H_ + ht * 16 + l16] = o[ht][r] * KINV / lrow[r];
  } else {
#pragma unroll
    for (int r = 0; r < 4; r++){
      size_t R = (size_t)b * S_ + m0 + quad * 4 + r;
#pragma unroll
      for (int ht = 0; ht < 8; ht++)
        po[((size_t)sp * NR_ + R) * H_ + ht * 16 + l16] = o[ht][r] * KINV;
      if (l16 == 0) pl[(size_t)sp * NR_ + R] = lrow[r];
    }
  }
}

// ---------------------------------------------------------------------------
__global__ void combine(const float* __restrict__ po, const float* __restrict__ pl,
                        float* __restrict__ out, int split){
  int row = blockIdx.x;
  int col = threadIdx.x;
  float num = 0.f, den = 0.f;
  for (int s = 0; s < split; s++){
    num += po[((size_t)s * NR_ + row) * H_ + col];
    den += pl[(size_t)s * NR_ + row];
  }
  out[(size_t)row * H_ + col] = num / den;
}

// ---------------------------------------------------------------------------
extern "C" void kernel_launch(void* const* d_in, const int* in_sizes, int n_in,
                              void* d_out, int out_size, void* d_ws, size_t ws_size,
                              hipStream_t stream){
  const float* x  = (const float*)d_in[0];
  const float* wq = (const float*)d_in[1];
  const float* wk = (const float*)d_in[2];
  const float* wv = (const float*)d_in[3];
  const float* du = (const float*)d_in[4];
  float* out = (float*)d_out;

  const size_t MiB = 1048576;
  char* ws = (char*)d_ws;
  short* qm = (short*)(ws);                      // 4 MiB
  short* km = (short*)(ws + 4 * MiB);            // 4 MiB
  short* vt = (short*)(ws + 8 * MiB);            // 4 MiB
  short* xb = (short*)(ws + 12 * MiB);           // 32 MiB
  short* wt = (short*)(ws + 44 * MiB);           // 768 KiB
  float* pl = (float*)(ws + 45 * MiB);           // split*64 KiB
  float* po = (float*)(ws + 45 * MiB + 524288);  // split*8 MiB

  size_t base  = 45 * MiB + 524288;
  size_t needA = base + 32 * MiB;
  size_t needB = base + 16 * MiB;
  int split = (ws_size >= needA) ? 4 : (ws_size >= needB) ? 2 : 1;

  hipLaunchKernelGGL(prep,     dim3(8576),        dim3(256), 0, stream, x, wq, wk, wv, xb, wt);
  hipLaunchKernelGGL(qkv_gemm, dim3(3, 128),      dim3(256), 0, stream, xb, wt, qm, km, vt);
  hipLaunchKernelGGL(attn,     dim3(128 * split), dim3(512), 0, stream,
                     qm, km, vt, du, po, pl, out, split);
  if (split > 1)
    hipLaunchKernelGGL(combine, dim3(NR_), dim3(H_), 0, stream, po, pl, out, split);
}